// Round 7
// baseline (226.481 us; speedup 1.0000x reference)
//
#include <hip/hip_runtime.h>
#include <stdint.h>

typedef __bf16 bf16x8 __attribute__((ext_vector_type(8)));
typedef float floatx4 __attribute__((ext_vector_type(4)));
typedef unsigned short ushort_t;

__device__ __forceinline__ ushort_t bf16rne(float f) {
    union { float f; unsigned u; } v; v.f = f;
    return (ushort_t)((v.u + 0x7fffu + ((v.u >> 16) & 1u)) >> 16);
}

// packed f32x2 -> bf16x2 (RNE), one VALU op (no builtin on gfx950 -> asm)
__device__ __forceinline__ unsigned cvt_pk_bf16(float lo, float hi) {
    unsigned r;
    asm("v_cvt_pk_bf16_f32 %0, %1, %2" : "=v"(r) : "v"(lo), "v"(hi));
    return r;
}

// async global->LDS, 16B per lane; LDS dest = base + lane*16 (wave-uniform base)
__device__ __forceinline__ void gl_lds16(const ushort_t* g, ushort_t* l) {
    __builtin_amdgcn_global_load_lds(
        (const __attribute__((address_space(1))) unsigned int*)g,
        (__attribute__((address_space(3))) unsigned int*)l, 16, 0, 0);
}

// Round 19: 256x256 / 8-wave / counted-vmcnt restructure (T3+T4 regime).
// Rounds 1/3/4/6: five schedules all pinned at MfmaUtil 28-29% = the m233
// 2-phase structural ceiling. Port the m201-regime geometry:
//  - 512 threads (8 waves, 2M x 4N), block tile M=256 x N=256, K=512.
//    Expert block: A = [W1_e0^T; W1_e1^T] (contiguous in ew1t). Router block:
//    A = rw1t. SAME GEMM1 template for both. Grid 640+128 = 768 = 3 gens.
//  - GEMM1 pipeline: 16 k-halves (32-k) through 4 LDS slots (4x32KB=128KB).
//    Entry per half: s_waitcnt vmcnt(8) + s_barrier (halves h+1,h+2 = 8 DMAs
//    in flight; in-order vmcnt semantics -> half h fully landed). DMAs for
//    half h+3 issued mid-half. vmcnt NEVER drains to 0 until the tail.
//  - sH1 unified layout [kh 0..7][nt 0..15][512 elems] = 128KB overlaid on
//    the GEMM1 slots after the final drain. Expert e0 -> kh 0-3, e1 -> kh 4-7
//    (= wrow*4 + (i>>1)); router rh1 0..255 -> kh 0-7. One epilogue for both.
//  - GEMM2: A (w2 / rw2) in REGISTERS (16 x bf16x8, round-5-verified load
//    pattern, once per pass), B from sH1. Expert: 2 passes (e0, e1), fresh
//    acc2 + GEMM3 + chart each. Router: 2 K-chunks accumulating, then logits.
// LDS 128KB + ~6KB tables -> 1 block/CU; __launch_bounds__(512,2) caps VGPR 256.

#define WAIT_VM_BAR(n) do { asm volatile("s_waitcnt vmcnt(" #n ")" ::: "memory"); __builtin_amdgcn_s_barrier(); } while (0)
#define WAIT_LG_BAR()  do { asm volatile("s_waitcnt lgkmcnt(0)" ::: "memory"); __builtin_amdgcn_s_barrier(); } while (0)

// ---------------- prep: convert x + 4 LDS-tiled weight transposes ------------
__global__ void prep(const float* __restrict__ x, ushort_t* __restrict__ x16,
                     const float* __restrict__ ew1, ushort_t* __restrict__ ew1t,
                     const float* __restrict__ ew2, ushort_t* __restrict__ ew2t,
                     const float* __restrict__ rw1, ushort_t* __restrict__ rw1t,
                     const float* __restrict__ rw2, ushort_t* __restrict__ rw2t) {
    __shared__ ushort_t sT[64 * 65];
    int b = blockIdx.x, tid = threadIdx.x;
    if (b < 16384) {
        int i = b * 256 + tid;   // 16,777,216/4 float4s
        float4 f = ((const float4*)x)[i];
        union { ushort_t s[4]; uint2 v; } pk;
        pk.s[0] = bf16rne(f.x); pk.s[1] = bf16rne(f.y);
        pk.s[2] = bf16rne(f.z); pk.s[3] = bf16rne(f.w);
        ((uint2*)x16)[i] = pk.v;
        return;
    }
    // 64x64 tile transpose: in fp32 [K][N] -> out bf16 [N][K]
    const float* in; ushort_t* outp; int K, N, k0, n0;
    int i = b - 16384;
    if (i < 160) {        // ew1 [10][512][128]
        int e = i >> 4, t = i & 15;
        in = ew1 + e * 65536; outp = ew1t + e * 65536;
        K = 512; N = 128; k0 = (t >> 1) * 64; n0 = (t & 1) * 64;
    } else if (i < 200) { // ew2 [10][128][128]
        i -= 160; int e = i >> 2, t = i & 3;
        in = ew2 + e * 16384; outp = ew2t + e * 16384;
        K = 128; N = 128; k0 = (t >> 1) * 64; n0 = (t & 1) * 64;
    } else if (i < 232) { // rw1 [512][256]
        i -= 200; in = rw1; outp = rw1t;
        K = 512; N = 256; k0 = (i >> 2) * 64; n0 = (i & 3) * 64;
    } else {              // rw2 [256][128]
        i -= 232; in = rw2; outp = rw2t;
        K = 256; N = 128; k0 = (i >> 1) * 64; n0 = (i & 1) * 64;
    }
    {
        int c = tid & 63, r0 = tid >> 6;
#pragma unroll
        for (int p = 0; p < 16; ++p) {
            int r = r0 * 16 + p;
            sT[c * 65 + r] = bf16rne(in[(size_t)(k0 + r) * N + n0 + c]);
        }
        __syncthreads();
        int rr = tid & 63, c0 = tid >> 6;
#pragma unroll
        for (int p = 0; p < 16; ++p) {
            int cc = c0 * 16 + p;
            outp[(size_t)(n0 + cc) * K + k0 + rr] = sT[cc * 65 + rr];
        }
    }
}

// --------- merged main: ids 0..127 = router blocks, 128..767 = expert pairs
__global__ __launch_bounds__(512, 2)
void fused_main(const ushort_t* __restrict__ x16,
                const ushort_t* __restrict__ rw1t, const float* __restrict__ rb1,
                const ushort_t* __restrict__ rw2t, const float* __restrict__ rb2f,
                const float* __restrict__ rw3, const float* __restrict__ rb3,
                const float* __restrict__ u,
                const ushort_t* __restrict__ ew1t, const ushort_t* __restrict__ ew2t,
                const float* __restrict__ eb1, const float* __restrict__ eb2,
                const float* __restrict__ ew3, const float* __restrict__ eb3,
                float* __restrict__ wts, float* __restrict__ chart) {
    // sU: 128 KB. GEMM1: 4 slots x 32KB (A-half 16KB @ +0, B-half 16KB @ +8192
    // elems). After GEMM1: sH1 [kh][nt][512] = the whole 128 KB.
    __shared__ alignas(16) ushort_t sU[65536];
    __shared__ float sB1p[256];
    __shared__ float sB2p[256];
    __shared__ float sW3[512];
    __shared__ float zbuf[256][2];

    const int tid = threadIdx.x;
    const int id = blockIdx.x;
    const int wave = tid >> 6, lane = tid & 63;
    const int ln15 = lane & 15, q = lane >> 4;
    const int wrow = wave & 1, wcol = wave >> 1;      // 2(M) x 4(N) wave grid
    const int rl = lane >> 2, cl = lane & 3;
    const int sw = (cl ^ ((rl >> 1) & 3)) * 8;        // staging swizzle (verified)
    const int fslot = (4 * ln15 + (q ^ ((ln15 >> 1) & 3))) * 8;  // frag read (verified)

    const bool rt = id < 128;
    int rb2g, e0 = 0;
    if (rt) {
        rb2g = (id & 7) * 16 + (id >> 3);             // XCD-aligned
    } else {
        int eid = id - 128, xcd = eid & 7, le = eid >> 3;
        int pr = le % 5;
        rb2g = xcd * 16 + le / 5;                     // same-XCD as router for this x-group
        e0 = pr * 2;
    }

    const ushort_t* Ab = rt ? rw1t : ew1t + (size_t)e0 * 65536;  // 256 x 512 (pair contiguous)
    const ushort_t* Bb = x16 + (size_t)rb2g * 256 * 512;         // 256 x 512

    // ---- staging: half h = k-range [h*32, h*32+32), slot h&3 ----
    auto stage_A = [&](int h) {   // 2 DMA/wave: A groups wave*2, wave*2+1
        int slot = (h & 3) * 16384;
        int g0 = wave * 2, g1 = g0 + 1;
        gl_lds16(Ab + (size_t)(g0 * 16 + rl) * 512 + h * 32 + sw, &sU[slot + g0 * 512]);
        gl_lds16(Ab + (size_t)(g1 * 16 + rl) * 512 + h * 32 + sw, &sU[slot + g1 * 512]);
    };
    auto stage_B = [&](int h) {   // 2 DMA/wave
        int slot = (h & 3) * 16384 + 8192;
        int g0 = wave * 2, g1 = g0 + 1;
        gl_lds16(Bb + (size_t)(g0 * 16 + rl) * 512 + h * 32 + sw, &sU[slot + g0 * 512]);
        gl_lds16(Bb + (size_t)(g1 * 16 + rl) * 512 + h * 32 + sw, &sU[slot + g1 * 512]);
    };

    // prologue: halves 0,1,2 in flight (12 DMA/wave)
    stage_A(0); stage_B(0); stage_A(1); stage_B(1); stage_A(2); stage_B(2);

    // small tables AFTER the prologue issues (extra per-wave vmcnt entries are
    // benign: entry waits keep the NEWEST 8 = halves h+1,h+2; everything older
    // -- including these -- is drained)
    if (rt) {
        if (tid < 256) sB1p[tid] = rb1[tid];
        if (tid < 128) sB2p[tid] = rb2f[tid];
    } else {
        if (tid < 256) { sB1p[tid] = eb1[e0 * 128 + tid]; sB2p[tid] = eb2[e0 * 128 + tid]; }
        sW3[tid] = ew3[e0 * 256 + tid];
    }

    floatx4 acc[8][4];
#pragma unroll
    for (int i = 0; i < 8; ++i)
#pragma unroll
        for (int j = 0; j < 4; ++j) acc[i][j] = (floatx4){0.f, 0.f, 0.f, 0.f};

    // one k-half: 12 ds_read + 32 MFMA + (optional) 4 DMA for half h+3
    auto gemm1_half = [&](int h, bool pf) {
        int slot = (h & 3) * 16384;
        bf16x8 b[4], a[4];
#pragma unroll
        for (int t = 0; t < 4; ++t) b[t] = *(const bf16x8*)(&sU[slot + 8192 + (wcol * 4 + t) * 512 + fslot]);
#pragma unroll
        for (int i2 = 0; i2 < 4; ++i2) a[i2] = *(const bf16x8*)(&sU[slot + (wrow * 8 + i2) * 512 + fslot]);
        if (pf) stage_A(h + 3);
        __builtin_amdgcn_s_setprio(1);
#pragma unroll
        for (int i2 = 0; i2 < 4; ++i2)
#pragma unroll
            for (int t = 0; t < 4; ++t)
                acc[i2][t] = __builtin_amdgcn_mfma_f32_16x16x32_bf16(a[i2], b[t], acc[i2][t], 0, 0, 0);
        __builtin_amdgcn_s_setprio(0);
#pragma unroll
        for (int i2 = 0; i2 < 4; ++i2) a[i2] = *(const bf16x8*)(&sU[slot + (wrow * 8 + 4 + i2) * 512 + fslot]);
        if (pf) stage_B(h + 3);
        __builtin_amdgcn_s_setprio(1);
#pragma unroll
        for (int i2 = 0; i2 < 4; ++i2)
#pragma unroll
            for (int t = 0; t < 4; ++t)
                acc[4 + i2][t] = __builtin_amdgcn_mfma_f32_16x16x32_bf16(a[i2], b[t], acc[4 + i2][t], 0, 0, 0);
        __builtin_amdgcn_s_setprio(0);
    };

    // vmcnt ledger (per wave, in-order): at entry of half h, outstanding ⊆
    // {half h(4), h+1(4), h+2(4)}; vmcnt(8) drains through half h.
#pragma unroll 1
    for (int h = 0; h < 14; ++h) {
        WAIT_VM_BAR(8);
        gemm1_half(h, h < 13);
    }
    WAIT_VM_BAR(4); gemm1_half(14, false);
    WAIT_VM_BAR(0); gemm1_half(15, false);
    __builtin_amdgcn_s_barrier();          // all waves done reading slots

    // ---- GEMM2 pass-0 A preload (w2_e0 / rw2 chunk0) -> regs, under epilogue ----
    const ushort_t* W2p0 = rt ? rw2t : ew2t + (size_t)e0 * 16384;
    const ushort_t* W2p1 = rt ? rw2t : ew2t + (size_t)(e0 + 1) * 16384;
    const int w2str = rt ? 256 : 128;
    const int w2off1 = rt ? 128 : 0;       // router chunk1 k-offset within row
    bf16x8 a2[4][4];
#pragma unroll
    for (int t = 0; t < 4; ++t)
#pragma unroll
        for (int khl = 0; khl < 4; ++khl)
            a2[t][khl] = *(const bf16x8*)(W2p0 + (size_t)(wrow * 64 + t * 16 + ln15) * w2str + khl * 32 + q * 8);

    // ---- epilogue (shared): acc -> relu+bias -> sH1 [kh][nt][512] ----
    // o = wrow*128 + i*16 + q*4 + r ; kh = wrow*4 + (i>>1) ; within-32 k' =
    // (i&1)*16 + q*4 + r -> lane' q-part = (i&1)*2 + (q>>1), elems (q&1)*4+r.
#pragma unroll
    for (int i = 0; i < 8; ++i) {
        int kh = wrow * 4 + (i >> 1);
        int qp = (i & 1) * 2 + (q >> 1);
        int o = wrow * 128 + i * 16 + q * 4;
#pragma unroll
        for (int j = 0; j < 4; ++j) {
            float v0 = fmaxf(acc[i][j][0] + sB1p[o + 0], 0.f);
            float v1 = fmaxf(acc[i][j][1] + sB1p[o + 1], 0.f);
            float v2 = fmaxf(acc[i][j][2] + sB1p[o + 2], 0.f);
            float v3 = fmaxf(acc[i][j][3] + sB1p[o + 3], 0.f);
            uint2 pk;
            pk.x = cvt_pk_bf16(v0, v1);
            pk.y = cvt_pk_bf16(v2, v3);
            *(uint2*)(&sU[kh * 8192 + (wcol * 4 + j) * 512 + qp * 128 + ln15 * 8 + (q & 1) * 4]) = pk;
        }
    }
    WAIT_LG_BAR();                         // sH1 visible everywhere

    if (!rt) {
        // ================= expert: 2 passes (e0: kh 0-3, e1: kh 4-7) ==========
#pragma unroll 1
        for (int ex = 0; ex < 2; ++ex) {
            if (ex == 1) {
#pragma unroll
                for (int t = 0; t < 4; ++t)
#pragma unroll
                    for (int khl = 0; khl < 4; ++khl)
                        a2[t][khl] = *(const bf16x8*)(W2p1 + (size_t)(wrow * 64 + t * 16 + ln15) * 128 + khl * 32 + q * 8);
            }
            floatx4 acc2[4][4];
#pragma unroll
            for (int im = 0; im < 4; ++im)
#pragma unroll
                for (int jn = 0; jn < 4; ++jn) acc2[im][jn] = (floatx4){0.f, 0.f, 0.f, 0.f};
            int khB = ex * 4;
#pragma unroll
            for (int khl = 0; khl < 4; ++khl) {
                bf16x8 b2[4];
#pragma unroll
                for (int t = 0; t < 4; ++t)
                    b2[t] = *(const bf16x8*)(&sU[(khB + khl) * 8192 + (wcol * 4 + t) * 512 + lane * 8]);
                __builtin_amdgcn_s_setprio(1);
#pragma unroll
                for (int im = 0; im < 4; ++im)
#pragma unroll
                    for (int jn = 0; jn < 4; ++jn)
                        acc2[im][jn] = __builtin_amdgcn_mfma_f32_16x16x32_bf16(a2[im][khl], b2[jn], acc2[im][jn], 0, 0, 0);
                __builtin_amdgcn_s_setprio(0);
            }
            // GEMM3 (L=2): o2 = wrow*64 + im*16 + q*4 + r
            float zc0[4] = {0.f, 0.f, 0.f, 0.f}, zc1[4] = {0.f, 0.f, 0.f, 0.f};
#pragma unroll
            for (int im = 0; im < 4; ++im) {
                int o0 = wrow * 64 + im * 16 + q * 4;
#pragma unroll
                for (int r = 0; r < 4; ++r) {
                    int o2 = o0 + r;
                    float w3a = sW3[ex * 256 + 2 * o2], w3b = sW3[ex * 256 + 2 * o2 + 1];
                    float bias = sB2p[ex * 128 + o2];
#pragma unroll
                    for (int jn = 0; jn < 4; ++jn) {
                        float val = fmaxf(acc2[im][jn][r] + bias, 0.f);
                        zc0[jn] += val * w3a;
                        zc1[jn] += val * w3b;
                    }
                }
            }
#pragma unroll
            for (int jn = 0; jn < 4; ++jn) {
                zc0[jn] += __shfl_xor(zc0[jn], 16, 64);
                zc0[jn] += __shfl_xor(zc0[jn], 32, 64);
                zc1[jn] += __shfl_xor(zc1[jn], 16, 64);
                zc1[jn] += __shfl_xor(zc1[jn], 32, 64);
            }
            if (wrow == 0 && q == 0) {
#pragma unroll
                for (int jn = 0; jn < 4; ++jn) {
                    int row = wcol * 64 + jn * 16 + ln15;
                    zbuf[row][0] = zc0[jn];
                    zbuf[row][1] = zc1[jn];
                }
            }
            __syncthreads();
            if (wrow == 1 && q == 0) {
#pragma unroll
                for (int jn = 0; jn < 4; ++jn) {
                    int row = wcol * 64 + jn * 16 + ln15;
                    zbuf[row][0] += zc0[jn];
                    zbuf[row][1] += zc1[jn];
                }
            }
            __syncthreads();
            {
                int row = tid >> 1, l = tid & 1;
                int grow = rb2g * 256 + row;
                chart[(size_t)(e0 + ex) * 65536 + (size_t)grow * 2 + l] = zbuf[row][l] + eb3[(e0 + ex) * 2 + l];
            }
            __syncthreads();   // zbuf reuse guard
        }
    } else {
        // ================= router: GEMM2 K=256 (2 chunks), logits, softmax =====
        floatx4 acc2[4][4];
#pragma unroll
        for (int im = 0; im < 4; ++im)
#pragma unroll
            for (int jn = 0; jn < 4; ++jn) acc2[im][jn] = (floatx4){0.f, 0.f, 0.f, 0.f};
#pragma unroll 1
        for (int c = 0; c < 2; ++c) {
            if (c == 1) {
#pragma unroll
                for (int t = 0; t < 4; ++t)
#pragma unroll
                    for (int khl = 0; khl < 4; ++khl)
                        a2[t][khl] = *(const bf16x8*)(W2p1 + (size_t)(wrow * 64 + t * 16 + ln15) * 256 + w2off1 + khl * 32 + q * 8);
            }
#pragma unroll
            for (int khl = 0; khl < 4; ++khl) {
                bf16x8 b2[4];
#pragma unroll
                for (int t = 0; t < 4; ++t)
                    b2[t] = *(const bf16x8*)(&sU[(c * 4 + khl) * 8192 + (wcol * 4 + t) * 512 + lane * 8]);
                __builtin_amdgcn_s_setprio(1);
#pragma unroll
                for (int im = 0; im < 4; ++im)
#pragma unroll
                    for (int jn = 0; jn < 4; ++jn)
                        acc2[im][jn] = __builtin_amdgcn_mfma_f32_16x16x32_bf16(a2[im][khl], b2[jn], acc2[im][jn], 0, 0, 0);
                __builtin_amdgcn_s_setprio(0);
            }
        }
        // logits: sw3r/lgbuf overlay on sU (after all GEMM2 reads done)
        __syncthreads();
        float* sw3r = (float*)sU;                     // 1280 floats @ bytes [0,5120)
        float* lgbuf = (float*)(&sU[2560]);           // 2560 floats @ bytes [5120,15360)
        for (int i2 = tid; i2 < 1280; i2 += 512) sw3r[i2] = rw3[i2];
        __syncthreads();

        float lg[4][10];
#pragma unroll
        for (int jn = 0; jn < 4; ++jn)
#pragma unroll
            for (int ee = 0; ee < 10; ++ee) lg[jn][ee] = 0.f;
#pragma unroll
        for (int im = 0; im < 4; ++im) {
            int o0 = wrow * 64 + im * 16 + q * 4;
#pragma unroll
            for (int r = 0; r < 4; ++r) {
                int o2 = o0 + r;
                float bias = sB2p[o2];
                const float* w3r = &sw3r[o2 * 10];
#pragma unroll
                for (int jn = 0; jn < 4; ++jn) {
                    float val = fmaxf(acc2[im][jn][r] + bias, 0.f);
#pragma unroll
                    for (int ee = 0; ee < 10; ++ee) lg[jn][ee] += val * w3r[ee];
                }
            }
        }
#pragma unroll
        for (int jn = 0; jn < 4; ++jn)
#pragma unroll
            for (int ee = 0; ee < 10; ++ee) {
                lg[jn][ee] += __shfl_xor(lg[jn][ee], 16, 64);
                lg[jn][ee] += __shfl_xor(lg[jn][ee], 32, 64);
            }
        if (wrow == 0 && q == 0) {
#pragma unroll
            for (int jn = 0; jn < 4; ++jn) {
                int row = wcol * 64 + jn * 16 + ln15;
#pragma unroll
                for (int ee = 0; ee < 10; ++ee) lgbuf[row * 10 + ee] = lg[jn][ee];
            }
        }
        __syncthreads();
        if (wrow == 1 && q == 0) {
#pragma unroll
            for (int jn = 0; jn < 4; ++jn) {
                int row = wcol * 64 + jn * 16 + ln15;
#pragma unroll
                for (int ee = 0; ee < 10; ++ee) lgbuf[row * 10 + ee] += lg[jn][ee];
            }
        }
        __syncthreads();
        if (tid < 256) {
            int grow = rb2g * 256 + tid;
            float v[10], mx = -1e30f;
#pragma unroll
            for (int ee = 0; ee < 10; ++ee) {
                float uu = u[(size_t)grow * 10 + ee];
                uu = fminf(fmaxf(uu, 1e-10f), 1.0f);
                float g = -logf(-logf(uu) + 1e-10f);
                v[ee] = (lgbuf[tid * 10 + ee] + rb3[ee] + g) * (1.0f / 3.0f);
                mx = fmaxf(mx, v[ee]);
            }
            float s = 0.f;
#pragma unroll
            for (int ee = 0; ee < 10; ++ee) { v[ee] = expf(v[ee] - mx); s += v[ee]; }
            float inv = 1.0f / s;
#pragma unroll
            for (int ee = 0; ee < 10; ++ee) wts[(size_t)grow * 10 + ee] = v[ee] * inv;
        }
    }
}

// ---------------- final z = sum_e weights * chart ------------------
__global__ void z_final(const float* __restrict__ w, const float* __restrict__ chart,
                        float* __restrict__ z) {
    __shared__ float swt[2560];
    int b0 = blockIdx.x * 256;
    for (int i = threadIdx.x; i < 2560; i += 256) swt[i] = w[(size_t)b0 * 10 + i];
    __syncthreads();
    int row = b0 + threadIdx.x;
    float z0 = 0.f, z1 = 0.f;
#pragma unroll
    for (int e = 0; e < 10; ++e) {
        float we = swt[threadIdx.x * 10 + e];
        float2 c = *(const float2*)(&chart[(size_t)e * 65536 + (size_t)row * 2]);
        z0 += we * c.x;
        z1 += we * c.y;
    }
    float2 o; o.x = z0; o.y = z1;
    *(float2*)(&z[(size_t)row * 2]) = o;
}

extern "C" void kernel_launch(void* const* d_in, const int* in_sizes, int n_in,
                              void* d_out, int out_size, void* d_ws, size_t ws_size,
                              hipStream_t stream) {
    const float* x = (const float*)d_in[0];
    const float* u = (const float*)d_in[1];
    const float* rw1 = (const float*)d_in[2];
    const float* rb1 = (const float*)d_in[3];
    const float* rw2 = (const float*)d_in[4];
    const float* rb2 = (const float*)d_in[5];
    const float* rw3 = (const float*)d_in[6];
    const float* rb3 = (const float*)d_in[7];
    const float* ew1 = (const float*)d_in[8];
    const float* eb1 = (const float*)d_in[9];
    const float* ew2 = (const float*)d_in[10];
    const float* eb2 = (const float*)d_in[11];
    const float* ew3 = (const float*)d_in[12];
    const float* eb3 = (const float*)d_in[13];
    float* out = (float*)d_out;
    float* z = out;                 // [32768, 2]
    float* wts = out + 65536;       // [32768, 10]
    float* chart = out + 393216;    // [10, 32768, 2]

    // workspace layout (bf16 elems), all 16B-aligned
    ushort_t* x16  = (ushort_t*)d_ws;            // 32768*512  = 16,777,216
    ushort_t* ew1t = x16 + 16777216;             // 10*128*512 =    655,360
    ushort_t* ew2t = ew1t + 655360;              // 10*128*128 =    163,840
    ushort_t* rw1t = ew2t + 163840;              // 256*512    =    131,072
    ushort_t* rw2t = rw1t + 131072;              // 128*256    =     32,768

    prep<<<16624, 256, 0, stream>>>(x, x16, ew1, ew1t, ew2, ew2t, rw1, rw1t, rw2, rw2t);

    fused_main<<<768, 512, 0, stream>>>(x16, rw1t, rb1, rw2t, rb2, rw3, rb3, u,
                                        ew1t, ew2t, eb1, eb2, ew3, eb3,
                                        wts, chart);

    z_final<<<128, 256, 0, stream>>>(wts, chart, z);
}

// Round 8
// 225.769 us; speedup vs baseline: 1.0032x; 1.0032x over previous
//
#include <hip/hip_runtime.h>
#include <stdint.h>

typedef __bf16 bf16x8 __attribute__((ext_vector_type(8)));
typedef float floatx4 __attribute__((ext_vector_type(4)));
typedef unsigned short ushort_t;

__device__ __forceinline__ ushort_t bf16rne(float f) {
    union { float f; unsigned u; } v; v.f = f;
    return (ushort_t)((v.u + 0x7fffu + ((v.u >> 16) & 1u)) >> 16);
}

// packed f32x2 -> bf16x2 (RNE), one VALU op (no builtin on gfx950 -> asm)
__device__ __forceinline__ unsigned cvt_pk_bf16(float lo, float hi) {
    unsigned r;
    asm("v_cvt_pk_bf16_f32 %0, %1, %2" : "=v"(r) : "v"(lo), "v"(hi));
    return r;
}

// async global->LDS, 16B per lane; LDS dest = base + lane*16 (wave-uniform base)
__device__ __forceinline__ void gl_lds16(const ushort_t* g, ushort_t* l) {
    __builtin_amdgcn_global_load_lds(
        (const __attribute__((address_space(1))) unsigned int*)g,
        (__attribute__((address_space(3))) unsigned int*)l, 16, 0, 0);
}

// Round 20: round-19 structure with the SPILL fixed. Round-19's
// __launch_bounds__(512,2) capped the allocator at 128 VGPR vs ~230 live
// (acc[8][4]=128 + a2 preload 64 + staging) -> scratch spill (WRITE_SIZE
// 3.8->56 MB, FETCH +22 MB, 108 us). (512,1) lifts the cap; 8 waves =
// 2/SIMD still fits at 256 VGPR, LDS 137KB already forces 1 block/CU, so
// occupancy is unchanged. Everything else identical to round 19.

#define WAIT_VM_BAR(n) do { asm volatile("s_waitcnt vmcnt(" #n ")" ::: "memory"); __builtin_amdgcn_s_barrier(); } while (0)
#define WAIT_LG_BAR()  do { asm volatile("s_waitcnt lgkmcnt(0)" ::: "memory"); __builtin_amdgcn_s_barrier(); } while (0)

// ---------------- prep: convert x + 4 LDS-tiled weight transposes ------------
__global__ void prep(const float* __restrict__ x, ushort_t* __restrict__ x16,
                     const float* __restrict__ ew1, ushort_t* __restrict__ ew1t,
                     const float* __restrict__ ew2, ushort_t* __restrict__ ew2t,
                     const float* __restrict__ rw1, ushort_t* __restrict__ rw1t,
                     const float* __restrict__ rw2, ushort_t* __restrict__ rw2t) {
    __shared__ ushort_t sT[64 * 65];
    int b = blockIdx.x, tid = threadIdx.x;
    if (b < 16384) {
        int i = b * 256 + tid;   // 16,777,216/4 float4s
        float4 f = ((const float4*)x)[i];
        union { ushort_t s[4]; uint2 v; } pk;
        pk.s[0] = bf16rne(f.x); pk.s[1] = bf16rne(f.y);
        pk.s[2] = bf16rne(f.z); pk.s[3] = bf16rne(f.w);
        ((uint2*)x16)[i] = pk.v;
        return;
    }
    // 64x64 tile transpose: in fp32 [K][N] -> out bf16 [N][K]
    const float* in; ushort_t* outp; int K, N, k0, n0;
    int i = b - 16384;
    if (i < 160) {        // ew1 [10][512][128]
        int e = i >> 4, t = i & 15;
        in = ew1 + e * 65536; outp = ew1t + e * 65536;
        K = 512; N = 128; k0 = (t >> 1) * 64; n0 = (t & 1) * 64;
    } else if (i < 200) { // ew2 [10][128][128]
        i -= 160; int e = i >> 2, t = i & 3;
        in = ew2 + e * 16384; outp = ew2t + e * 16384;
        K = 128; N = 128; k0 = (t >> 1) * 64; n0 = (t & 1) * 64;
    } else if (i < 232) { // rw1 [512][256]
        i -= 200; in = rw1; outp = rw1t;
        K = 512; N = 256; k0 = (i >> 2) * 64; n0 = (i & 3) * 64;
    } else {              // rw2 [256][128]
        i -= 232; in = rw2; outp = rw2t;
        K = 256; N = 128; k0 = (i >> 1) * 64; n0 = (i & 1) * 64;
    }
    {
        int c = tid & 63, r0 = tid >> 6;
#pragma unroll
        for (int p = 0; p < 16; ++p) {
            int r = r0 * 16 + p;
            sT[c * 65 + r] = bf16rne(in[(size_t)(k0 + r) * N + n0 + c]);
        }
        __syncthreads();
        int rr = tid & 63, c0 = tid >> 6;
#pragma unroll
        for (int p = 0; p < 16; ++p) {
            int cc = c0 * 16 + p;
            outp[(size_t)(n0 + cc) * K + k0 + rr] = sT[cc * 65 + rr];
        }
    }
}

// --------- merged main: ids 0..127 = router blocks, 128..767 = expert pairs
__global__ __launch_bounds__(512, 1)
void fused_main(const ushort_t* __restrict__ x16,
                const ushort_t* __restrict__ rw1t, const float* __restrict__ rb1,
                const ushort_t* __restrict__ rw2t, const float* __restrict__ rb2f,
                const float* __restrict__ rw3, const float* __restrict__ rb3,
                const float* __restrict__ u,
                const ushort_t* __restrict__ ew1t, const ushort_t* __restrict__ ew2t,
                const float* __restrict__ eb1, const float* __restrict__ eb2,
                const float* __restrict__ ew3, const float* __restrict__ eb3,
                float* __restrict__ wts, float* __restrict__ chart) {
    // sU: 128 KB. GEMM1: 4 slots x 32KB (A-half 16KB @ +0, B-half 16KB @ +8192
    // elems). After GEMM1: sH1 [kh][nt][512] = the whole 128 KB.
    __shared__ alignas(16) ushort_t sU[65536];
    __shared__ float sB1p[256];
    __shared__ float sB2p[256];
    __shared__ float sW3[512];
    __shared__ float zbuf[256][2];

    const int tid = threadIdx.x;
    const int id = blockIdx.x;
    const int wave = tid >> 6, lane = tid & 63;
    const int ln15 = lane & 15, q = lane >> 4;
    const int wrow = wave & 1, wcol = wave >> 1;      // 2(M) x 4(N) wave grid
    const int rl = lane >> 2, cl = lane & 3;
    const int sw = (cl ^ ((rl >> 1) & 3)) * 8;        // staging swizzle (verified)
    const int fslot = (4 * ln15 + (q ^ ((ln15 >> 1) & 3))) * 8;  // frag read (verified)

    const bool rt = id < 128;
    int rb2g, e0 = 0;
    if (rt) {
        rb2g = (id & 7) * 16 + (id >> 3);             // XCD-aligned
    } else {
        int eid = id - 128, xcd = eid & 7, le = eid >> 3;
        int pr = le % 5;
        rb2g = xcd * 16 + le / 5;                     // same-XCD as router for this x-group
        e0 = pr * 2;
    }

    const ushort_t* Ab = rt ? rw1t : ew1t + (size_t)e0 * 65536;  // 256 x 512 (pair contiguous)
    const ushort_t* Bb = x16 + (size_t)rb2g * 256 * 512;         // 256 x 512

    // ---- staging: half h = k-range [h*32, h*32+32), slot h&3 ----
    auto stage_A = [&](int h) {   // 2 DMA/wave: A groups wave*2, wave*2+1
        int slot = (h & 3) * 16384;
        int g0 = wave * 2, g1 = g0 + 1;
        gl_lds16(Ab + (size_t)(g0 * 16 + rl) * 512 + h * 32 + sw, &sU[slot + g0 * 512]);
        gl_lds16(Ab + (size_t)(g1 * 16 + rl) * 512 + h * 32 + sw, &sU[slot + g1 * 512]);
    };
    auto stage_B = [&](int h) {   // 2 DMA/wave
        int slot = (h & 3) * 16384 + 8192;
        int g0 = wave * 2, g1 = g0 + 1;
        gl_lds16(Bb + (size_t)(g0 * 16 + rl) * 512 + h * 32 + sw, &sU[slot + g0 * 512]);
        gl_lds16(Bb + (size_t)(g1 * 16 + rl) * 512 + h * 32 + sw, &sU[slot + g1 * 512]);
    };

    // prologue: halves 0,1,2 in flight (12 DMA/wave)
    stage_A(0); stage_B(0); stage_A(1); stage_B(1); stage_A(2); stage_B(2);

    // small tables AFTER the prologue issues (extra per-wave vmcnt entries are
    // benign: entry waits keep the NEWEST 8 = halves h+1,h+2; everything older
    // -- including these -- is drained)
    if (rt) {
        if (tid < 256) sB1p[tid] = rb1[tid];
        if (tid < 128) sB2p[tid] = rb2f[tid];
    } else {
        if (tid < 256) { sB1p[tid] = eb1[e0 * 128 + tid]; sB2p[tid] = eb2[e0 * 128 + tid]; }
        sW3[tid] = ew3[e0 * 256 + tid];
    }

    floatx4 acc[8][4];
#pragma unroll
    for (int i = 0; i < 8; ++i)
#pragma unroll
        for (int j = 0; j < 4; ++j) acc[i][j] = (floatx4){0.f, 0.f, 0.f, 0.f};

    // one k-half: 12 ds_read + 32 MFMA + (optional) 4 DMA for half h+3
    auto gemm1_half = [&](int h, bool pf) {
        int slot = (h & 3) * 16384;
        bf16x8 b[4], a[4];
#pragma unroll
        for (int t = 0; t < 4; ++t) b[t] = *(const bf16x8*)(&sU[slot + 8192 + (wcol * 4 + t) * 512 + fslot]);
#pragma unroll
        for (int i2 = 0; i2 < 4; ++i2) a[i2] = *(const bf16x8*)(&sU[slot + (wrow * 8 + i2) * 512 + fslot]);
        if (pf) stage_A(h + 3);
        __builtin_amdgcn_s_setprio(1);
#pragma unroll
        for (int i2 = 0; i2 < 4; ++i2)
#pragma unroll
            for (int t = 0; t < 4; ++t)
                acc[i2][t] = __builtin_amdgcn_mfma_f32_16x16x32_bf16(a[i2], b[t], acc[i2][t], 0, 0, 0);
        __builtin_amdgcn_s_setprio(0);
#pragma unroll
        for (int i2 = 0; i2 < 4; ++i2) a[i2] = *(const bf16x8*)(&sU[slot + (wrow * 8 + 4 + i2) * 512 + fslot]);
        if (pf) stage_B(h + 3);
        __builtin_amdgcn_s_setprio(1);
#pragma unroll
        for (int i2 = 0; i2 < 4; ++i2)
#pragma unroll
            for (int t = 0; t < 4; ++t)
                acc[4 + i2][t] = __builtin_amdgcn_mfma_f32_16x16x32_bf16(a[i2], b[t], acc[4 + i2][t], 0, 0, 0);
        __builtin_amdgcn_s_setprio(0);
    };

    // vmcnt ledger (per wave, in-order): at entry of half h, outstanding ⊆
    // {half h(4), h+1(4), h+2(4)}; vmcnt(8) drains through half h.
#pragma unroll 1
    for (int h = 0; h < 14; ++h) {
        WAIT_VM_BAR(8);
        gemm1_half(h, h < 13);
    }
    WAIT_VM_BAR(4); gemm1_half(14, false);
    WAIT_VM_BAR(0); gemm1_half(15, false);
    __builtin_amdgcn_s_barrier();          // all waves done reading slots

    // ---- GEMM2 pass-0 A preload (w2_e0 / rw2 chunk0) -> regs, under epilogue ----
    const ushort_t* W2p0 = rt ? rw2t : ew2t + (size_t)e0 * 16384;
    const ushort_t* W2p1 = rt ? rw2t : ew2t + (size_t)(e0 + 1) * 16384;
    const int w2str = rt ? 256 : 128;
    const int w2off1 = rt ? 128 : 0;       // router chunk1 k-offset within row
    bf16x8 a2[4][4];
#pragma unroll
    for (int t = 0; t < 4; ++t)
#pragma unroll
        for (int khl = 0; khl < 4; ++khl)
            a2[t][khl] = *(const bf16x8*)(W2p0 + (size_t)(wrow * 64 + t * 16 + ln15) * w2str + khl * 32 + q * 8);

    // ---- epilogue (shared): acc -> relu+bias -> sH1 [kh][nt][512] ----
    // o = wrow*128 + i*16 + q*4 + r ; kh = wrow*4 + (i>>1) ; within-32 k' =
    // (i&1)*16 + q*4 + r -> lane' q-part = (i&1)*2 + (q>>1), elems (q&1)*4+r.
#pragma unroll
    for (int i = 0; i < 8; ++i) {
        int kh = wrow * 4 + (i >> 1);
        int qp = (i & 1) * 2 + (q >> 1);
        int o = wrow * 128 + i * 16 + q * 4;
#pragma unroll
        for (int j = 0; j < 4; ++j) {
            float v0 = fmaxf(acc[i][j][0] + sB1p[o + 0], 0.f);
            float v1 = fmaxf(acc[i][j][1] + sB1p[o + 1], 0.f);
            float v2 = fmaxf(acc[i][j][2] + sB1p[o + 2], 0.f);
            float v3 = fmaxf(acc[i][j][3] + sB1p[o + 3], 0.f);
            uint2 pk;
            pk.x = cvt_pk_bf16(v0, v1);
            pk.y = cvt_pk_bf16(v2, v3);
            *(uint2*)(&sU[kh * 8192 + (wcol * 4 + j) * 512 + qp * 128 + ln15 * 8 + (q & 1) * 4]) = pk;
        }
    }
    WAIT_LG_BAR();                         // sH1 visible everywhere

    if (!rt) {
        // ================= expert: 2 passes (e0: kh 0-3, e1: kh 4-7) ==========
#pragma unroll 1
        for (int ex = 0; ex < 2; ++ex) {
            if (ex == 1) {
#pragma unroll
                for (int t = 0; t < 4; ++t)
#pragma unroll
                    for (int khl = 0; khl < 4; ++khl)
                        a2[t][khl] = *(const bf16x8*)(W2p1 + (size_t)(wrow * 64 + t * 16 + ln15) * 128 + khl * 32 + q * 8);
            }
            floatx4 acc2[4][4];
#pragma unroll
            for (int im = 0; im < 4; ++im)
#pragma unroll
                for (int jn = 0; jn < 4; ++jn) acc2[im][jn] = (floatx4){0.f, 0.f, 0.f, 0.f};
            int khB = ex * 4;
#pragma unroll
            for (int khl = 0; khl < 4; ++khl) {
                bf16x8 b2[4];
#pragma unroll
                for (int t = 0; t < 4; ++t)
                    b2[t] = *(const bf16x8*)(&sU[(khB + khl) * 8192 + (wcol * 4 + t) * 512 + lane * 8]);
                __builtin_amdgcn_s_setprio(1);
#pragma unroll
                for (int im = 0; im < 4; ++im)
#pragma unroll
                    for (int jn = 0; jn < 4; ++jn)
                        acc2[im][jn] = __builtin_amdgcn_mfma_f32_16x16x32_bf16(a2[im][khl], b2[jn], acc2[im][jn], 0, 0, 0);
                __builtin_amdgcn_s_setprio(0);
            }
            // GEMM3 (L=2): o2 = wrow*64 + im*16 + q*4 + r
            float zc0[4] = {0.f, 0.f, 0.f, 0.f}, zc1[4] = {0.f, 0.f, 0.f, 0.f};
#pragma unroll
            for (int im = 0; im < 4; ++im) {
                int o0 = wrow * 64 + im * 16 + q * 4;
#pragma unroll
                for (int r = 0; r < 4; ++r) {
                    int o2 = o0 + r;
                    float w3a = sW3[ex * 256 + 2 * o2], w3b = sW3[ex * 256 + 2 * o2 + 1];
                    float bias = sB2p[ex * 128 + o2];
#pragma unroll
                    for (int jn = 0; jn < 4; ++jn) {
                        float val = fmaxf(acc2[im][jn][r] + bias, 0.f);
                        zc0[jn] += val * w3a;
                        zc1[jn] += val * w3b;
                    }
                }
            }
#pragma unroll
            for (int jn = 0; jn < 4; ++jn) {
                zc0[jn] += __shfl_xor(zc0[jn], 16, 64);
                zc0[jn] += __shfl_xor(zc0[jn], 32, 64);
                zc1[jn] += __shfl_xor(zc1[jn], 16, 64);
                zc1[jn] += __shfl_xor(zc1[jn], 32, 64);
            }
            if (wrow == 0 && q == 0) {
#pragma unroll
                for (int jn = 0; jn < 4; ++jn) {
                    int row = wcol * 64 + jn * 16 + ln15;
                    zbuf[row][0] = zc0[jn];
                    zbuf[row][1] = zc1[jn];
                }
            }
            __syncthreads();
            if (wrow == 1 && q == 0) {
#pragma unroll
                for (int jn = 0; jn < 4; ++jn) {
                    int row = wcol * 64 + jn * 16 + ln15;
                    zbuf[row][0] += zc0[jn];
                    zbuf[row][1] += zc1[jn];
                }
            }
            __syncthreads();
            {
                int row = tid >> 1, l = tid & 1;
                int grow = rb2g * 256 + row;
                chart[(size_t)(e0 + ex) * 65536 + (size_t)grow * 2 + l] = zbuf[row][l] + eb3[(e0 + ex) * 2 + l];
            }
            __syncthreads();   // zbuf reuse guard
        }
    } else {
        // ================= router: GEMM2 K=256 (2 chunks), logits, softmax =====
        floatx4 acc2[4][4];
#pragma unroll
        for (int im = 0; im < 4; ++im)
#pragma unroll
            for (int jn = 0; jn < 4; ++jn) acc2[im][jn] = (floatx4){0.f, 0.f, 0.f, 0.f};
#pragma unroll 1
        for (int c = 0; c < 2; ++c) {
            if (c == 1) {
#pragma unroll
                for (int t = 0; t < 4; ++t)
#pragma unroll
                    for (int khl = 0; khl < 4; ++khl)
                        a2[t][khl] = *(const bf16x8*)(W2p1 + (size_t)(wrow * 64 + t * 16 + ln15) * 256 + w2off1 + khl * 32 + q * 8);
            }
#pragma unroll
            for (int khl = 0; khl < 4; ++khl) {
                bf16x8 b2[4];
#pragma unroll
                for (int t = 0; t < 4; ++t)
                    b2[t] = *(const bf16x8*)(&sU[(c * 4 + khl) * 8192 + (wcol * 4 + t) * 512 + lane * 8]);
                __builtin_amdgcn_s_setprio(1);
#pragma unroll
                for (int im = 0; im < 4; ++im)
#pragma unroll
                    for (int jn = 0; jn < 4; ++jn)
                        acc2[im][jn] = __builtin_amdgcn_mfma_f32_16x16x32_bf16(a2[im][khl], b2[jn], acc2[im][jn], 0, 0, 0);
                __builtin_amdgcn_s_setprio(0);
            }
        }
        // logits: sw3r/lgbuf overlay on sU (after all GEMM2 reads done)
        __syncthreads();
        float* sw3r = (float*)sU;                     // 1280 floats @ bytes [0,5120)
        float* lgbuf = (float*)(&sU[2560]);           // 2560 floats @ bytes [5120,15360)
        for (int i2 = tid; i2 < 1280; i2 += 512) sw3r[i2] = rw3[i2];
        __syncthreads();

        float lg[4][10];
#pragma unroll
        for (int jn = 0; jn < 4; ++jn)
#pragma unroll
            for (int ee = 0; ee < 10; ++ee) lg[jn][ee] = 0.f;
#pragma unroll
        for (int im = 0; im < 4; ++im) {
            int o0 = wrow * 64 + im * 16 + q * 4;
#pragma unroll
            for (int r = 0; r < 4; ++r) {
                int o2 = o0 + r;
                float bias = sB2p[o2];
                const float* w3r = &sw3r[o2 * 10];
#pragma unroll
                for (int jn = 0; jn < 4; ++jn) {
                    float val = fmaxf(acc2[im][jn][r] + bias, 0.f);
#pragma unroll
                    for (int ee = 0; ee < 10; ++ee) lg[jn][ee] += val * w3r[ee];
                }
            }
        }
#pragma unroll
        for (int jn = 0; jn < 4; ++jn)
#pragma unroll
            for (int ee = 0; ee < 10; ++ee) {
                lg[jn][ee] += __shfl_xor(lg[jn][ee], 16, 64);
                lg[jn][ee] += __shfl_xor(lg[jn][ee], 32, 64);
            }
        if (wrow == 0 && q == 0) {
#pragma unroll
            for (int jn = 0; jn < 4; ++jn) {
                int row = wcol * 64 + jn * 16 + ln15;
#pragma unroll
                for (int ee = 0; ee < 10; ++ee) lgbuf[row * 10 + ee] = lg[jn][ee];
            }
        }
        __syncthreads();
        if (wrow == 1 && q == 0) {
#pragma unroll
            for (int jn = 0; jn < 4; ++jn) {
                int row = wcol * 64 + jn * 16 + ln15;
#pragma unroll
                for (int ee = 0; ee < 10; ++ee) lgbuf[row * 10 + ee] += lg[jn][ee];
            }
        }
        __syncthreads();
        if (tid < 256) {
            int grow = rb2g * 256 + tid;
            float v[10], mx = -1e30f;
#pragma unroll
            for (int ee = 0; ee < 10; ++ee) {
                float uu = u[(size_t)grow * 10 + ee];
                uu = fminf(fmaxf(uu, 1e-10f), 1.0f);
                float g = -logf(-logf(uu) + 1e-10f);
                v[ee] = (lgbuf[tid * 10 + ee] + rb3[ee] + g) * (1.0f / 3.0f);
                mx = fmaxf(mx, v[ee]);
            }
            float s = 0.f;
#pragma unroll
            for (int ee = 0; ee < 10; ++ee) { v[ee] = expf(v[ee] - mx); s += v[ee]; }
            float inv = 1.0f / s;
#pragma unroll
            for (int ee = 0; ee < 10; ++ee) wts[(size_t)grow * 10 + ee] = v[ee] * inv;
        }
    }
}

// ---------------- final z = sum_e weights * chart ------------------
__global__ void z_final(const float* __restrict__ w, const float* __restrict__ chart,
                        float* __restrict__ z) {
    __shared__ float swt[2560];
    int b0 = blockIdx.x * 256;
    for (int i = threadIdx.x; i < 2560; i += 256) swt[i] = w[(size_t)b0 * 10 + i];
    __syncthreads();
    int row = b0 + threadIdx.x;
    float z0 = 0.f, z1 = 0.f;
#pragma unroll
    for (int e = 0; e < 10; ++e) {
        float we = swt[threadIdx.x * 10 + e];
        float2 c = *(const float2*)(&chart[(size_t)e * 65536 + (size_t)row * 2]);
        z0 += we * c.x;
        z1 += we * c.y;
    }
    float2 o; o.x = z0; o.y = z1;
    *(float2*)(&z[(size_t)row * 2]) = o;
}

extern "C" void kernel_launch(void* const* d_in, const int* in_sizes, int n_in,
                              void* d_out, int out_size, void* d_ws, size_t ws_size,
                              hipStream_t stream) {
    const float* x = (const float*)d_in[0];
    const float* u = (const float*)d_in[1];
    const float* rw1 = (const float*)d_in[2];
    const float* rb1 = (const float*)d_in[3];
    const float* rw2 = (const float*)d_in[4];
    const float* rb2 = (const float*)d_in[5];
    const float* rw3 = (const float*)d_in[6];
    const float* rb3 = (const float*)d_in[7];
    const float* ew1 = (const float*)d_in[8];
    const float* eb1 = (const float*)d_in[9];
    const float* ew2 = (const float*)d_in[10];
    const float* eb2 = (const float*)d_in[11];
    const float* ew3 = (const float*)d_in[12];
    const float* eb3 = (const float*)d_in[13];
    float* out = (float*)d_out;
    float* z = out;                 // [32768, 2]
    float* wts = out + 65536;       // [32768, 10]
    float* chart = out + 393216;    // [10, 32768, 2]

    // workspace layout (bf16 elems), all 16B-aligned
    ushort_t* x16  = (ushort_t*)d_ws;            // 32768*512  = 16,777,216
    ushort_t* ew1t = x16 + 16777216;             // 10*128*512 =    655,360
    ushort_t* ew2t = ew1t + 655360;              // 10*128*128 =    163,840
    ushort_t* rw1t = ew2t + 163840;              // 256*512    =    131,072
    ushort_t* rw2t = rw1t + 131072;              // 128*256    =     32,768

    prep<<<16624, 256, 0, stream>>>(x, x16, ew1, ew1t, ew2, ew2t, rw1, rw1t, rw2, rw2t);

    fused_main<<<768, 512, 0, stream>>>(x16, rw1t, rb1, rw2t, rb2, rw3, rb3, u,
                                        ew1t, ew2t, eb1, eb2, ew3, eb3,
                                        wts, chart);

    z_final<<<128, 256, 0, stream>>>(wts, chart, z);
}

// Round 9
// 204.990 us; speedup vs baseline: 1.1048x; 1.1014x over previous
//
#include <hip/hip_runtime.h>
#include <stdint.h>

typedef __bf16 bf16x8 __attribute__((ext_vector_type(8)));
typedef float floatx4 __attribute__((ext_vector_type(4)));
typedef unsigned short ushort_t;

__device__ __forceinline__ ushort_t bf16rne(float f) {
    union { float f; unsigned u; } v; v.f = f;
    return (ushort_t)((v.u + 0x7fffu + ((v.u >> 16) & 1u)) >> 16);
}

// packed f32x2 -> bf16x2 (RNE), one VALU op (no builtin on gfx950 -> asm)
__device__ __forceinline__ unsigned cvt_pk_bf16(float lo, float hi) {
    unsigned r;
    asm("v_cvt_pk_bf16_f32 %0, %1, %2" : "=v"(r) : "v"(lo), "v"(hi));
    return r;
}

// async global->LDS, 16B per lane; LDS dest = base + lane*16 (wave-uniform base)
__device__ __forceinline__ void gl_lds16(const ushort_t* g, ushort_t* l) {
    __builtin_amdgcn_global_load_lds(
        (const __attribute__((address_space(1))) unsigned int*)g,
        (__attribute__((address_space(3))) unsigned int*)l, 16, 0, 0);
}

// Round 21: kill the arch-VGPR spill in the 8-wave structure. hipcc pins
// 512-thread blocks at 128 ARCH VGPRs (acc lives in AGPRs; m98 convention:
// vgpr/agpr reported separately). Round 19/20's a2[4][4] preload (64 arch
// regs) hoisted across the epilogue overflowed the 128 budget by ~33 regs ->
// 52 MB scratch traffic (WRITE 3.8->56 MB). Fix: per-khl A-fragment loads
// with a 2-slot register pipeline (a2p[2][4] = 32 transient regs, static
// indexing), khl+1 prefetched under khl's MFMA; slot 0 prefetched before the
// epilogue. Router GEMM2 = one 8-step (c,khl) pipeline. Rest identical.

#define WAIT_VM_BAR(n) do { asm volatile("s_waitcnt vmcnt(" #n ")" ::: "memory"); __builtin_amdgcn_s_barrier(); } while (0)
#define WAIT_LG_BAR()  do { asm volatile("s_waitcnt lgkmcnt(0)" ::: "memory"); __builtin_amdgcn_s_barrier(); } while (0)

// ---------------- prep: convert x + 4 LDS-tiled weight transposes ------------
__global__ void prep(const float* __restrict__ x, ushort_t* __restrict__ x16,
                     const float* __restrict__ ew1, ushort_t* __restrict__ ew1t,
                     const float* __restrict__ ew2, ushort_t* __restrict__ ew2t,
                     const float* __restrict__ rw1, ushort_t* __restrict__ rw1t,
                     const float* __restrict__ rw2, ushort_t* __restrict__ rw2t) {
    __shared__ ushort_t sT[64 * 65];
    int b = blockIdx.x, tid = threadIdx.x;
    if (b < 16384) {
        int i = b * 256 + tid;   // 16,777,216/4 float4s
        float4 f = ((const float4*)x)[i];
        union { ushort_t s[4]; uint2 v; } pk;
        pk.s[0] = bf16rne(f.x); pk.s[1] = bf16rne(f.y);
        pk.s[2] = bf16rne(f.z); pk.s[3] = bf16rne(f.w);
        ((uint2*)x16)[i] = pk.v;
        return;
    }
    // 64x64 tile transpose: in fp32 [K][N] -> out bf16 [N][K]
    const float* in; ushort_t* outp; int K, N, k0, n0;
    int i = b - 16384;
    if (i < 160) {        // ew1 [10][512][128]
        int e = i >> 4, t = i & 15;
        in = ew1 + e * 65536; outp = ew1t + e * 65536;
        K = 512; N = 128; k0 = (t >> 1) * 64; n0 = (t & 1) * 64;
    } else if (i < 200) { // ew2 [10][128][128]
        i -= 160; int e = i >> 2, t = i & 3;
        in = ew2 + e * 16384; outp = ew2t + e * 16384;
        K = 128; N = 128; k0 = (t >> 1) * 64; n0 = (t & 1) * 64;
    } else if (i < 232) { // rw1 [512][256]
        i -= 200; in = rw1; outp = rw1t;
        K = 512; N = 256; k0 = (i >> 2) * 64; n0 = (i & 3) * 64;
    } else {              // rw2 [256][128]
        i -= 232; in = rw2; outp = rw2t;
        K = 256; N = 128; k0 = (i >> 1) * 64; n0 = (i & 1) * 64;
    }
    {
        int c = tid & 63, r0 = tid >> 6;
#pragma unroll
        for (int p = 0; p < 16; ++p) {
            int r = r0 * 16 + p;
            sT[c * 65 + r] = bf16rne(in[(size_t)(k0 + r) * N + n0 + c]);
        }
        __syncthreads();
        int rr = tid & 63, c0 = tid >> 6;
#pragma unroll
        for (int p = 0; p < 16; ++p) {
            int cc = c0 * 16 + p;
            outp[(size_t)(n0 + cc) * K + k0 + rr] = sT[cc * 65 + rr];
        }
    }
}

// --------- merged main: ids 0..127 = router blocks, 128..767 = expert pairs
__global__ __launch_bounds__(512, 1)
void fused_main(const ushort_t* __restrict__ x16,
                const ushort_t* __restrict__ rw1t, const float* __restrict__ rb1,
                const ushort_t* __restrict__ rw2t, const float* __restrict__ rb2f,
                const float* __restrict__ rw3, const float* __restrict__ rb3,
                const float* __restrict__ u,
                const ushort_t* __restrict__ ew1t, const ushort_t* __restrict__ ew2t,
                const float* __restrict__ eb1, const float* __restrict__ eb2,
                const float* __restrict__ ew3, const float* __restrict__ eb3,
                float* __restrict__ wts, float* __restrict__ chart) {
    // sU: 128 KB. GEMM1: 4 slots x 32KB (A-half 16KB @ +0, B-half 16KB @ +8192
    // elems). After GEMM1: sH1 [kh][nt][512] = the whole 128 KB.
    __shared__ alignas(16) ushort_t sU[65536];
    __shared__ float sB1p[256];
    __shared__ float sB2p[256];
    __shared__ float sW3[512];
    __shared__ float zbuf[256][2];

    const int tid = threadIdx.x;
    const int id = blockIdx.x;
    const int wave = tid >> 6, lane = tid & 63;
    const int ln15 = lane & 15, q = lane >> 4;
    const int wrow = wave & 1, wcol = wave >> 1;      // 2(M) x 4(N) wave grid
    const int rl = lane >> 2, cl = lane & 3;
    const int sw = (cl ^ ((rl >> 1) & 3)) * 8;        // staging swizzle (verified)
    const int fslot = (4 * ln15 + (q ^ ((ln15 >> 1) & 3))) * 8;  // frag read (verified)

    const bool rt = id < 128;
    int rb2g, e0 = 0;
    if (rt) {
        rb2g = (id & 7) * 16 + (id >> 3);             // XCD-aligned
    } else {
        int eid = id - 128, xcd = eid & 7, le = eid >> 3;
        int pr = le % 5;
        rb2g = xcd * 16 + le / 5;                     // same-XCD as router for this x-group
        e0 = pr * 2;
    }

    const ushort_t* Ab = rt ? rw1t : ew1t + (size_t)e0 * 65536;  // 256 x 512 (pair contiguous)
    const ushort_t* Bb = x16 + (size_t)rb2g * 256 * 512;         // 256 x 512

    // ---- staging: half h = k-range [h*32, h*32+32), slot h&3 ----
    auto stage_A = [&](int h) {   // 2 DMA/wave: A groups wave*2, wave*2+1
        int slot = (h & 3) * 16384;
        int g0 = wave * 2, g1 = g0 + 1;
        gl_lds16(Ab + (size_t)(g0 * 16 + rl) * 512 + h * 32 + sw, &sU[slot + g0 * 512]);
        gl_lds16(Ab + (size_t)(g1 * 16 + rl) * 512 + h * 32 + sw, &sU[slot + g1 * 512]);
    };
    auto stage_B = [&](int h) {   // 2 DMA/wave
        int slot = (h & 3) * 16384 + 8192;
        int g0 = wave * 2, g1 = g0 + 1;
        gl_lds16(Bb + (size_t)(g0 * 16 + rl) * 512 + h * 32 + sw, &sU[slot + g0 * 512]);
        gl_lds16(Bb + (size_t)(g1 * 16 + rl) * 512 + h * 32 + sw, &sU[slot + g1 * 512]);
    };

    // prologue: halves 0,1,2 in flight (12 DMA/wave)
    stage_A(0); stage_B(0); stage_A(1); stage_B(1); stage_A(2); stage_B(2);

    // small tables AFTER the prologue issues (the extra per-wave vmcnt entries
    // are absorbed by the h=0..2 entry waits; ledger re-synchronizes by h=3)
    if (rt) {
        if (tid < 256) sB1p[tid] = rb1[tid];
        if (tid < 128) sB2p[tid] = rb2f[tid];
    } else {
        if (tid < 256) { sB1p[tid] = eb1[e0 * 128 + tid]; sB2p[tid] = eb2[e0 * 128 + tid]; }
        sW3[tid] = ew3[e0 * 256 + tid];
    }

    floatx4 acc[8][4];
#pragma unroll
    for (int i = 0; i < 8; ++i)
#pragma unroll
        for (int j = 0; j < 4; ++j) acc[i][j] = (floatx4){0.f, 0.f, 0.f, 0.f};

    // one k-half: 12 ds_read + 32 MFMA + (optional) 4 DMA for half h+3
    auto gemm1_half = [&](int h, bool pf) {
        int slot = (h & 3) * 16384;
        bf16x8 b[4], a[4];
#pragma unroll
        for (int t = 0; t < 4; ++t) b[t] = *(const bf16x8*)(&sU[slot + 8192 + (wcol * 4 + t) * 512 + fslot]);
#pragma unroll
        for (int i2 = 0; i2 < 4; ++i2) a[i2] = *(const bf16x8*)(&sU[slot + (wrow * 8 + i2) * 512 + fslot]);
        if (pf) stage_A(h + 3);
        __builtin_amdgcn_s_setprio(1);
#pragma unroll
        for (int i2 = 0; i2 < 4; ++i2)
#pragma unroll
            for (int t = 0; t < 4; ++t)
                acc[i2][t] = __builtin_amdgcn_mfma_f32_16x16x32_bf16(a[i2], b[t], acc[i2][t], 0, 0, 0);
        __builtin_amdgcn_s_setprio(0);
#pragma unroll
        for (int i2 = 0; i2 < 4; ++i2) a[i2] = *(const bf16x8*)(&sU[slot + (wrow * 8 + 4 + i2) * 512 + fslot]);
        if (pf) stage_B(h + 3);
        __builtin_amdgcn_s_setprio(1);
#pragma unroll
        for (int i2 = 0; i2 < 4; ++i2)
#pragma unroll
            for (int t = 0; t < 4; ++t)
                acc[4 + i2][t] = __builtin_amdgcn_mfma_f32_16x16x32_bf16(a[i2], b[t], acc[4 + i2][t], 0, 0, 0);
        __builtin_amdgcn_s_setprio(0);
    };

    // vmcnt ledger (per wave, in-order): at entry of half h, outstanding ⊆
    // {half h(4), h+1(4), h+2(4)}; vmcnt(8) drains through half h.
#pragma unroll 1
    for (int h = 0; h < 14; ++h) {
        WAIT_VM_BAR(8);
        gemm1_half(h, h < 13);
    }
    WAIT_VM_BAR(4); gemm1_half(14, false);
    WAIT_VM_BAR(0); gemm1_half(15, false);
    __builtin_amdgcn_s_barrier();          // all waves done reading slots

    // ---- GEMM2 A-fragment loader: per-khl, 2-slot register pipeline ----
    // rows wrow*64 + t*16 + ln15 (stride str), k-offset koff + q*8.
    const ushort_t* W2p0 = rt ? rw2t : ew2t + (size_t)e0 * 16384;
    const ushort_t* W2p1 = rt ? rw2t : ew2t + (size_t)(e0 + 1) * 16384;
    auto loadA2 = [&](const ushort_t* W2, int str, int koff, bf16x8 (&dst)[4]) {
#pragma unroll
        for (int t = 0; t < 4; ++t)
            dst[t] = *(const bf16x8*)(W2 + (size_t)(wrow * 64 + t * 16 + ln15) * str + koff + q * 8);
    };

    bf16x8 a2p[2][4];
    loadA2(W2p0, rt ? 256 : 128, 0, a2p[0]);   // slot 0 prefetch under epilogue

    // ---- epilogue (shared): acc -> relu+bias -> sH1 [kh][nt][512] ----
#pragma unroll
    for (int i = 0; i < 8; ++i) {
        int kh = wrow * 4 + (i >> 1);
        int qp = (i & 1) * 2 + (q >> 1);
        int o = wrow * 128 + i * 16 + q * 4;
#pragma unroll
        for (int j = 0; j < 4; ++j) {
            float v0 = fmaxf(acc[i][j][0] + sB1p[o + 0], 0.f);
            float v1 = fmaxf(acc[i][j][1] + sB1p[o + 1], 0.f);
            float v2 = fmaxf(acc[i][j][2] + sB1p[o + 2], 0.f);
            float v3 = fmaxf(acc[i][j][3] + sB1p[o + 3], 0.f);
            uint2 pk;
            pk.x = cvt_pk_bf16(v0, v1);
            pk.y = cvt_pk_bf16(v2, v3);
            *(uint2*)(&sU[kh * 8192 + (wcol * 4 + j) * 512 + qp * 128 + ln15 * 8 + (q & 1) * 4]) = pk;
        }
    }
    WAIT_LG_BAR();                         // sH1 visible everywhere

    if (!rt) {
        // ================= expert: 2 passes (e0: kh 0-3, e1: kh 4-7) ==========
#pragma unroll 1
        for (int ex = 0; ex < 2; ++ex) {
            const ushort_t* W2 = ex ? W2p1 : W2p0;
            if (ex == 1) loadA2(W2, 128, 0, a2p[0]);
            floatx4 acc2[4][4];
#pragma unroll
            for (int im = 0; im < 4; ++im)
#pragma unroll
                for (int jn = 0; jn < 4; ++jn) acc2[im][jn] = (floatx4){0.f, 0.f, 0.f, 0.f};
#pragma unroll
            for (int khl = 0; khl < 4; ++khl) {
                if (khl < 3) loadA2(W2, 128, (khl + 1) * 32, a2p[(khl + 1) & 1]);
                bf16x8 b2[4];
#pragma unroll
                for (int t = 0; t < 4; ++t)
                    b2[t] = *(const bf16x8*)(&sU[(ex * 4 + khl) * 8192 + (wcol * 4 + t) * 512 + lane * 8]);
                __builtin_amdgcn_s_setprio(1);
#pragma unroll
                for (int im = 0; im < 4; ++im)
#pragma unroll
                    for (int jn = 0; jn < 4; ++jn)
                        acc2[im][jn] = __builtin_amdgcn_mfma_f32_16x16x32_bf16(a2p[khl & 1][im], b2[jn], acc2[im][jn], 0, 0, 0);
                __builtin_amdgcn_s_setprio(0);
            }
            // GEMM3 (L=2): o2 = wrow*64 + im*16 + q*4 + r
            float zc0[4] = {0.f, 0.f, 0.f, 0.f}, zc1[4] = {0.f, 0.f, 0.f, 0.f};
#pragma unroll
            for (int im = 0; im < 4; ++im) {
                int o0 = wrow * 64 + im * 16 + q * 4;
#pragma unroll
                for (int r = 0; r < 4; ++r) {
                    int o2 = o0 + r;
                    float w3a = sW3[ex * 256 + 2 * o2], w3b = sW3[ex * 256 + 2 * o2 + 1];
                    float bias = sB2p[ex * 128 + o2];
#pragma unroll
                    for (int jn = 0; jn < 4; ++jn) {
                        float val = fmaxf(acc2[im][jn][r] + bias, 0.f);
                        zc0[jn] += val * w3a;
                        zc1[jn] += val * w3b;
                    }
                }
            }
#pragma unroll
            for (int jn = 0; jn < 4; ++jn) {
                zc0[jn] += __shfl_xor(zc0[jn], 16, 64);
                zc0[jn] += __shfl_xor(zc0[jn], 32, 64);
                zc1[jn] += __shfl_xor(zc1[jn], 16, 64);
                zc1[jn] += __shfl_xor(zc1[jn], 32, 64);
            }
            if (wrow == 0 && q == 0) {
#pragma unroll
                for (int jn = 0; jn < 4; ++jn) {
                    int row = wcol * 64 + jn * 16 + ln15;
                    zbuf[row][0] = zc0[jn];
                    zbuf[row][1] = zc1[jn];
                }
            }
            __syncthreads();
            if (wrow == 1 && q == 0) {
#pragma unroll
                for (int jn = 0; jn < 4; ++jn) {
                    int row = wcol * 64 + jn * 16 + ln15;
                    zbuf[row][0] += zc0[jn];
                    zbuf[row][1] += zc1[jn];
                }
            }
            __syncthreads();
            {
                int row = tid >> 1, l = tid & 1;
                int grow = rb2g * 256 + row;
                chart[(size_t)(e0 + ex) * 65536 + (size_t)grow * 2 + l] = zbuf[row][l] + eb3[(e0 + ex) * 2 + l];
            }
            __syncthreads();   // zbuf reuse guard
        }
    } else {
        // ================= router: GEMM2 K=256 as one 8-step pipeline ========
        floatx4 acc2[4][4];
#pragma unroll
        for (int im = 0; im < 4; ++im)
#pragma unroll
            for (int jn = 0; jn < 4; ++jn) acc2[im][jn] = (floatx4){0.f, 0.f, 0.f, 0.f};
#pragma unroll
        for (int s = 0; s < 8; ++s) {      // s = c*4 + khl ; kh index = s
            if (s < 7) {
                int sn = s + 1;
                loadA2(rw2t, 256, (sn >> 2) * 128 + (sn & 3) * 32, a2p[(s + 1) & 1]);
            }
            bf16x8 b2[4];
#pragma unroll
            for (int t = 0; t < 4; ++t)
                b2[t] = *(const bf16x8*)(&sU[s * 8192 + (wcol * 4 + t) * 512 + lane * 8]);
            __builtin_amdgcn_s_setprio(1);
#pragma unroll
            for (int im = 0; im < 4; ++im)
#pragma unroll
                for (int jn = 0; jn < 4; ++jn)
                    acc2[im][jn] = __builtin_amdgcn_mfma_f32_16x16x32_bf16(a2p[s & 1][im], b2[jn], acc2[im][jn], 0, 0, 0);
            __builtin_amdgcn_s_setprio(0);
        }
        // logits: sw3r/lgbuf overlay on sU (after all GEMM2 reads done)
        __syncthreads();
        float* sw3r = (float*)sU;                     // 1280 floats @ bytes [0,5120)
        float* lgbuf = (float*)(&sU[2560]);           // 2560 floats @ bytes [5120,15360)
        for (int i2 = tid; i2 < 1280; i2 += 512) sw3r[i2] = rw3[i2];
        __syncthreads();

        float lg[4][10];
#pragma unroll
        for (int jn = 0; jn < 4; ++jn)
#pragma unroll
            for (int ee = 0; ee < 10; ++ee) lg[jn][ee] = 0.f;
#pragma unroll
        for (int im = 0; im < 4; ++im) {
            int o0 = wrow * 64 + im * 16 + q * 4;
#pragma unroll
            for (int r = 0; r < 4; ++r) {
                int o2 = o0 + r;
                float bias = sB2p[o2];
                const float* w3r = &sw3r[o2 * 10];
#pragma unroll
                for (int jn = 0; jn < 4; ++jn) {
                    float val = fmaxf(acc2[im][jn][r] + bias, 0.f);
#pragma unroll
                    for (int ee = 0; ee < 10; ++ee) lg[jn][ee] += val * w3r[ee];
                }
            }
        }
#pragma unroll
        for (int jn = 0; jn < 4; ++jn)
#pragma unroll
            for (int ee = 0; ee < 10; ++ee) {
                lg[jn][ee] += __shfl_xor(lg[jn][ee], 16, 64);
                lg[jn][ee] += __shfl_xor(lg[jn][ee], 32, 64);
            }
        if (wrow == 0 && q == 0) {
#pragma unroll
            for (int jn = 0; jn < 4; ++jn) {
                int row = wcol * 64 + jn * 16 + ln15;
#pragma unroll
                for (int ee = 0; ee < 10; ++ee) lgbuf[row * 10 + ee] = lg[jn][ee];
            }
        }
        __syncthreads();
        if (wrow == 1 && q == 0) {
#pragma unroll
            for (int jn = 0; jn < 4; ++jn) {
                int row = wcol * 64 + jn * 16 + ln15;
#pragma unroll
                for (int ee = 0; ee < 10; ++ee) lgbuf[row * 10 + ee] += lg[jn][ee];
            }
        }
        __syncthreads();
        if (tid < 256) {
            int grow = rb2g * 256 + tid;
            float v[10], mx = -1e30f;
#pragma unroll
            for (int ee = 0; ee < 10; ++ee) {
                float uu = u[(size_t)grow * 10 + ee];
                uu = fminf(fmaxf(uu, 1e-10f), 1.0f);
                float g = -logf(-logf(uu) + 1e-10f);
                v[ee] = (lgbuf[tid * 10 + ee] + rb3[ee] + g) * (1.0f / 3.0f);
                mx = fmaxf(mx, v[ee]);
            }
            float s = 0.f;
#pragma unroll
            for (int ee = 0; ee < 10; ++ee) { v[ee] = expf(v[ee] - mx); s += v[ee]; }
            float inv = 1.0f / s;
#pragma unroll
            for (int ee = 0; ee < 10; ++ee) wts[(size_t)grow * 10 + ee] = v[ee] * inv;
        }
    }
}

// ---------------- final z = sum_e weights * chart ------------------
__global__ void z_final(const float* __restrict__ w, const float* __restrict__ chart,
                        float* __restrict__ z) {
    __shared__ float swt[2560];
    int b0 = blockIdx.x * 256;
    for (int i = threadIdx.x; i < 2560; i += 256) swt[i] = w[(size_t)b0 * 10 + i];
    __syncthreads();
    int row = b0 + threadIdx.x;
    float z0 = 0.f, z1 = 0.f;
#pragma unroll
    for (int e = 0; e < 10; ++e) {
        float we = swt[threadIdx.x * 10 + e];
        float2 c = *(const float2*)(&chart[(size_t)e * 65536 + (size_t)row * 2]);
        z0 += we * c.x;
        z1 += we * c.y;
    }
    float2 o; o.x = z0; o.y = z1;
    *(float2*)(&z[(size_t)row * 2]) = o;
}

extern "C" void kernel_launch(void* const* d_in, const int* in_sizes, int n_in,
                              void* d_out, int out_size, void* d_ws, size_t ws_size,
                              hipStream_t stream) {
    const float* x = (const float*)d_in[0];
    const float* u = (const float*)d_in[1];
    const float* rw1 = (const float*)d_in[2];
    const float* rb1 = (const float*)d_in[3];
    const float* rw2 = (const float*)d_in[4];
    const float* rb2 = (const float*)d_in[5];
    const float* rw3 = (const float*)d_in[6];
    const float* rb3 = (const float*)d_in[7];
    const float* ew1 = (const float*)d_in[8];
    const float* eb1 = (const float*)d_in[9];
    const float* ew2 = (const float*)d_in[10];
    const float* eb2 = (const float*)d_in[11];
    const float* ew3 = (const float*)d_in[12];
    const float* eb3 = (const float*)d_in[13];
    float* out = (float*)d_out;
    float* z = out;                 // [32768, 2]
    float* wts = out + 65536;       // [32768, 10]
    float* chart = out + 393216;    // [10, 32768, 2]

    // workspace layout (bf16 elems), all 16B-aligned
    ushort_t* x16  = (ushort_t*)d_ws;            // 32768*512  = 16,777,216
    ushort_t* ew1t = x16 + 16777216;             // 10*128*512 =    655,360
    ushort_t* ew2t = ew1t + 655360;              // 10*128*128 =    163,840
    ushort_t* rw1t = ew2t + 163840;              // 256*512    =    131,072
    ushort_t* rw2t = rw1t + 131072;              // 128*256    =     32,768

    prep<<<16624, 256, 0, stream>>>(x, x16, ew1, ew1t, ew2, ew2t, rw1, rw1t, rw2, rw2t);

    fused_main<<<768, 512, 0, stream>>>(x16, rw1t, rb1, rw2t, rb2, rw3, rb3, u,
                                        ew1t, ew2t, eb1, eb2, ew3, eb3,
                                        wts, chart);

    z_final<<<128, 256, 0, stream>>>(wts, chart, z);
}